// Round 3
// baseline (480.548 us; speedup 1.0000x reference)
//
#include <hip/hip_runtime.h>
#include <stdint.h>

#define GLOBAL_AS __attribute__((address_space(1)))
#define LDS_AS __attribute__((address_space(3)))

typedef float f32x4 __attribute__((ext_vector_type(4)));
typedef short bf16x8 __attribute__((ext_vector_type(8)));

static __device__ __forceinline__ unsigned short f2b(float f) {
  union { float f; unsigned u; } v; v.f = f;
  return (unsigned short)((v.u + 0x7FFFu + ((v.u >> 16) & 1u)) >> 16);
}

static __device__ __forceinline__ void async16(const void* g, void* l) {
  __builtin_amdgcn_global_load_lds((const GLOBAL_AS unsigned int*)g,
                                   (LDS_AS unsigned int*)l, 16, 0, 0);
}

// ---------------- fused prep: cast_x | rope table | 4x transpose-cast ----------------
__global__ void prep_kernel(const float* __restrict__ x,
                            const float* __restrict__ Wq, const float* __restrict__ Wk,
                            const float* __restrict__ Wv, const float* __restrict__ Wo,
                            unsigned short* __restrict__ xb,
                            unsigned short* __restrict__ WcatT, unsigned short* __restrict__ WoT,
                            float* __restrict__ cosT, float* __restrict__ sinT) {
  __shared__ float tile[32][33];
  const int bid = blockIdx.x;
  const int tid = threadIdx.x;
  if (bid < 16384) {
    // cast x -> bf16, 4 elements/thread
    const int i = bid * 256 + tid;
    float4 v = ((const float4*)x)[i];
    ushort4 o;
    o.x = f2b(v.x); o.y = f2b(v.y); o.z = f2b(v.z); o.w = f2b(v.w);
    ((ushort4*)xb)[i] = o;
  } else if (bid < 16384 + 512) {
    const int idx = (bid - 16384) * 256 + tid;
    const int s = idx >> 5, j = idx & 31;
    float freq = expf(-((float)(2 * j) * (1.0f / 64.0f)) * 9.210340371976184f);
    float ang = (float)s * freq;
    float sn, cs;
    sincosf(ang, &sn, &cs);
    cosT[idx] = cs;
    sinT[idx] = sn;
  } else {
    const int t = bid - 16896;
    const int mat = t >> 10;
    const int r = t & 1023;
    const int k0 = (r & 31) * 32, n0 = (r >> 5) * 32;
    const float* W = (mat == 0) ? Wq : (mat == 1) ? Wk : (mat == 2) ? Wv : Wo;
    unsigned short* WT = (mat < 3) ? (WcatT + (size_t)mat * 1024 * 1024) : WoT;
    const int tx = tid & 31, ty = tid >> 5;
    #pragma unroll
    for (int i = 0; i < 4; i++)
      tile[ty + i * 8][tx] = W[(size_t)(k0 + ty + i * 8) * 1024 + n0 + tx];
    __syncthreads();
    #pragma unroll
    for (int i = 0; i < 4; i++)
      WT[(size_t)(n0 + ty + i * 8) * 1024 + k0 + tx] = f2b(tile[tx][ty + i * 8]);
  }
}

// ---------------- fused QKV GEMM ----------------
// A staged in LDS (BK=64, XOR-swizzled); B streamed global->VGPR (L2-resident, 6 MB).
__global__ __launch_bounds__(256)
void gemm_qkv_kernel(const unsigned short* __restrict__ xb,
                     const unsigned short* __restrict__ WT,
                     const float* __restrict__ cosT,
                     const float* __restrict__ sinT,
                     unsigned short* __restrict__ Qd,
                     unsigned short* __restrict__ KTd,
                     unsigned short* __restrict__ VTd) {
  __shared__ char sA[16384];
  const int tid = threadIdx.x;
  const int lane = tid & 63;
  const int wave = tid >> 6;
  const int lrow = lane & 15;
  const int quad = lane >> 4;
  const int m0 = blockIdx.x * 128;
  const int n0 = blockIdx.y * 128;
  const int wrow = (wave >> 1) * 64;
  const int wcol = (wave & 1) * 64;

  const f32x4 zf = {0.f, 0.f, 0.f, 0.f};
  f32x4 acc[4][4];
  #pragma unroll
  for (int i = 0; i < 4; i++)
    #pragma unroll
    for (int j = 0; j < 4; j++) acc[i][j] = zf;

  const int srow = tid >> 3;
  const int gcol = ((tid & 7) ^ (srow & 7)) * 8; // source-side swizzle chunk

  // per-lane B row base: rows n0+wcol+nt*16+lrow, 16B chunk at k = kt + (kk*4+quad)*8
  const unsigned short* Bb = WT + (size_t)(n0 + wcol + lrow) * 1024 + quad * 8;

  for (int kt = 0; kt < 1024; kt += 64) {
    __syncthreads();
    #pragma unroll
    for (int i = 0; i < 4; i++)
      async16(xb + (size_t)(m0 + i * 32 + srow) * 1024 + kt + gcol, &sA[i * 4096 + tid * 16]);
    bf16x8 bfr[2][4];
    #pragma unroll
    for (int kk = 0; kk < 2; kk++)
      #pragma unroll
      for (int nt = 0; nt < 4; nt++)
        bfr[kk][nt] = *(const bf16x8*)(Bb + (size_t)nt * 16384 + kt + kk * 32);
    __syncthreads();
    #pragma unroll
    for (int kk = 0; kk < 2; kk++) {
      const int kc = kk * 4 + quad;
      bf16x8 af[4];
      #pragma unroll
      for (int mt = 0; mt < 4; mt++) {
        const int row = wrow + mt * 16 + lrow;
        af[mt] = *(const bf16x8*)&sA[row * 128 + ((kc ^ (row & 7)) << 4)];
      }
      #pragma unroll
      for (int mt = 0; mt < 4; mt++)
        #pragma unroll
        for (int nt = 0; nt < 4; nt++)
          acc[mt][nt] = __builtin_amdgcn_mfma_f32_16x16x32_bf16(af[mt], bfr[kk][nt], acc[mt][nt], 0, 0, 0);
    }
  }

  const int b = m0 >> 12;
  const int sec = n0 >> 10;         // 0=Q 1=K 2=V
  const int s0 = (m0 & 4095) + wrow;
  const int c0 = (n0 & 1023) + wcol;

  if (sec == 2) {
    #pragma unroll
    for (int mt = 0; mt < 4; mt++) {
      const int sB4 = s0 + mt * 16 + quad * 4;
      #pragma unroll
      for (int nt = 0; nt < 4; nt++) {
        const int c = c0 + nt * 16 + lrow;
        const int h = c >> 6, e = c & 63;
        ushort4 pk;
        pk.x = f2b(acc[mt][nt][0]); pk.y = f2b(acc[mt][nt][1]);
        pk.z = f2b(acc[mt][nt][2]); pk.w = f2b(acc[mt][nt][3]);
        *(ushort4*)&VTd[((size_t)(b * 16 + h) * 64 + e) * 4096 + sB4] = pk;
      }
    }
  } else {
    #pragma unroll
    for (int mt = 0; mt < 4; mt++) {
      const int sB4 = s0 + mt * 16 + quad * 4;
      #pragma unroll
      for (int nt = 0; nt < 4; nt++) {
        const int c = c0 + nt * 16 + lrow;
        const int j = (c & 63) >> 1;
        float ov[4];
        #pragma unroll
        for (int r = 0; r < 4; r++) {
          const float v = acc[mt][nt][r];
          const float p = __shfl_xor(v, 1, 64);
          const int s = sB4 + r;
          const float cs = cosT[s * 32 + j];
          const float sn = sinT[s * 32 + j];
          const float t = (lane & 1) ? p * sn : -p * sn;
          ov[r] = fmaxf(fmaf(v, cs, t), 0.0f);
        }
        if (sec == 0) {
          const int grow = m0 + wrow + mt * 16 + quad * 4;
          #pragma unroll
          for (int r = 0; r < 4; r++)
            Qd[(size_t)(grow + r) * 1024 + c] = f2b(ov[r]);
        } else {
          const int h = c >> 6, d = c & 63;
          ushort4 pk;
          pk.x = f2b(ov[0]); pk.y = f2b(ov[1]); pk.z = f2b(ov[2]); pk.w = f2b(ov[3]);
          *(ushort4*)&KTd[((size_t)(b * 16 + h) * 64 + d) * 4096 + sB4] = pk;
        }
      }
    }
  }
}

// ---------------- vk = V_pad^T @ K  (per b,h; K-split partials) ----------------
__global__ __launch_bounds__(256)
void vk_partial_kernel(const unsigned short* __restrict__ KTd,
                       const unsigned short* __restrict__ VTd,
                       float* __restrict__ vkp) {
  __shared__ char sV[4096];
  __shared__ char sK[4096];
  const int tid = threadIdx.x;
  const int lane = tid & 63;
  const int wave = tid >> 6;
  const int lrow = lane & 15;
  const int quad = lane >> 4;
  const int bh = blockIdx.x;
  const int kb = blockIdx.y;
  const int s00 = kb * 512;

  const f32x4 zf = {0.f, 0.f, 0.f, 0.f};
  f32x4 acc[5];
  #pragma unroll
  for (int i = 0; i < 5; i++) acc[i] = zf;

  bf16x8 af4;
  const short oneb = (short)0x3F80;
  #pragma unroll
  for (int j = 0; j < 8; j++) af4[j] = (lrow == 0) ? oneb : (short)0;

  const int srow = tid >> 2;
  const int gcol = ((tid & 3) ^ (srow & 3)) * 8;

  for (int kt = 0; kt < 512; kt += 32) {
    __syncthreads();
    async16(VTd + ((size_t)bh * 64 + srow) * 4096 + s00 + kt + gcol, &sV[tid * 16]);
    async16(KTd + ((size_t)bh * 64 + srow) * 4096 + s00 + kt + gcol, &sK[tid * 16]);
    __syncthreads();
    const int rowK = wave * 16 + lrow;
    bf16x8 bfrag = *(const bf16x8*)&sK[rowK * 64 + ((quad ^ (rowK & 3)) << 4)];
    #pragma unroll
    for (int mt = 0; mt < 4; mt++) {
      const int rowV = mt * 16 + lrow;
      bf16x8 af = *(const bf16x8*)&sV[rowV * 64 + ((quad ^ (rowV & 3)) << 4)];
      acc[mt] = __builtin_amdgcn_mfma_f32_16x16x32_bf16(af, bfrag, acc[mt], 0, 0, 0);
    }
    acc[4] = __builtin_amdgcn_mfma_f32_16x16x32_bf16(af4, bfrag, acc[4], 0, 0, 0);
  }

  #pragma unroll
  for (int mt = 0; mt < 5; mt++) {
    #pragma unroll
    for (int r = 0; r < 4; r++) {
      const int e = mt * 16 + quad * 4 + r;
      const int d = wave * 16 + lrow;
      vkp[((size_t)(bh * 8 + kb) * 80 + e) * 64 + d] = acc[mt][r];
    }
  }
}

__global__ void vk_reduce_kernel(const float* __restrict__ vkp, unsigned short* __restrict__ vkb) {
  int idx = blockIdx.x * 256 + threadIdx.x;
  if (idx >= 64 * 80 * 64) return;
  int bh = idx / 5120, r = idx % 5120;
  float s = 0.f;
  #pragma unroll
  for (int kb = 0; kb < 8; kb++) s += vkp[(size_t)(bh * 8 + kb) * 5120 + r];
  vkb[idx] = f2b(s);
}

// ---------------- num + divide -> attn ----------------
__global__ __launch_bounds__(256)
void attn_kernel(const unsigned short* __restrict__ Qd,
                 const unsigned short* __restrict__ vkb,
                 unsigned short* __restrict__ attn) {
  __shared__ char sQ[32768];
  __shared__ char sVK[10240];
  const int tid = threadIdx.x;
  const int lane = tid & 63;
  const int wave = tid >> 6;
  const int lrow = lane & 15;
  const int quad = lane >> 4;
  const int bh = blockIdx.y, b = bh >> 4, h = bh & 15;
  const int l0 = b * 4096 + blockIdx.x * 256;

  const int c4 = tid & 7;
  #pragma unroll
  for (int r = 0; r < 8; r++) {
    const int o = r * 4096 + tid * 16;
    const int row = o >> 7;
    const int g4 = c4 ^ (row & 7);
    async16(Qd + (size_t)(l0 + row) * 1024 + h * 64 + g4 * 8, &sQ[o]);
  }
  {
    int row = tid >> 3;
    int g4 = c4 ^ (row & 7);
    async16(vkb + (size_t)bh * 5120 + row * 64 + g4 * 8, &sVK[tid * 16]);
    row += 32; g4 = c4 ^ (row & 7);
    async16(vkb + (size_t)bh * 5120 + row * 64 + g4 * 8, &sVK[4096 + tid * 16]);
    if (tid < 128) {
      row = 64 + (tid >> 3); g4 = c4 ^ (row & 7);
      async16(vkb + (size_t)bh * 5120 + row * 64 + g4 * 8, &sVK[8192 + tid * 16]);
    }
  }
  __syncthreads();

  const f32x4 zf = {0.f, 0.f, 0.f, 0.f};
  f32x4 acc[4][5];
  #pragma unroll
  for (int i = 0; i < 4; i++)
    #pragma unroll
    for (int j = 0; j < 5; j++) acc[i][j] = zf;

  #pragma unroll
  for (int kk = 0; kk < 2; kk++) {
    const int kc = kk * 4 + quad;
    bf16x8 af[4], bfr[5];
    #pragma unroll
    for (int mt = 0; mt < 4; mt++) {
      const int row = wave * 64 + mt * 16 + lrow;
      af[mt] = *(const bf16x8*)&sQ[row * 128 + ((kc ^ (row & 7)) << 4)];
    }
    #pragma unroll
    for (int nt = 0; nt < 5; nt++) {
      const int row = nt * 16 + lrow;
      bfr[nt] = *(const bf16x8*)&sVK[row * 128 + ((kc ^ (row & 7)) << 4)];
    }
    #pragma unroll
    for (int mt = 0; mt < 4; mt++)
      #pragma unroll
      for (int nt = 0; nt < 5; nt++)
        acc[mt][nt] = __builtin_amdgcn_mfma_f32_16x16x32_bf16(af[mt], bfr[nt], acc[mt][nt], 0, 0, 0);
  }

  #pragma unroll
  for (int mt = 0; mt < 4; mt++) {
    #pragma unroll
    for (int r = 0; r < 4; r++) {
      const float den = __shfl(acc[mt][4][r], lane & 48, 64);
      const float inv = 1.0f / (den + 1e-6f);
      const int l = l0 + wave * 64 + mt * 16 + quad * 4 + r;
      #pragma unroll
      for (int nt = 0; nt < 4; nt++)
        attn[(size_t)l * 1024 + h * 64 + nt * 16 + lrow] = f2b(acc[mt][nt][r] * inv);
    }
  }
}

// ---------------- out = attn @ Wo ----------------
// A staged in LDS; Wo^T streamed global->VGPR (2 MB, L2-resident).
__global__ __launch_bounds__(256)
void gemm_out_kernel(const unsigned short* __restrict__ A,
                     const unsigned short* __restrict__ BT,
                     float* __restrict__ C) {
  __shared__ char sA[16384];
  const int tid = threadIdx.x;
  const int lane = tid & 63;
  const int wave = tid >> 6;
  const int lrow = lane & 15;
  const int quad = lane >> 4;
  const int m0 = blockIdx.x * 128;
  const int n0 = blockIdx.y * 128;
  const int wrow = (wave >> 1) * 64;
  const int wcol = (wave & 1) * 64;

  const f32x4 zf = {0.f, 0.f, 0.f, 0.f};
  f32x4 acc[4][4];
  #pragma unroll
  for (int i = 0; i < 4; i++)
    #pragma unroll
    for (int j = 0; j < 4; j++) acc[i][j] = zf;

  const int srow = tid >> 3;
  const int gcol = ((tid & 7) ^ (srow & 7)) * 8;
  const unsigned short* Bb = BT + (size_t)(n0 + wcol + lrow) * 1024 + quad * 8;

  for (int kt = 0; kt < 1024; kt += 64) {
    __syncthreads();
    #pragma unroll
    for (int i = 0; i < 4; i++)
      async16(A + (size_t)(m0 + i * 32 + srow) * 1024 + kt + gcol, &sA[i * 4096 + tid * 16]);
    bf16x8 bfr[2][4];
    #pragma unroll
    for (int kk = 0; kk < 2; kk++)
      #pragma unroll
      for (int nt = 0; nt < 4; nt++)
        bfr[kk][nt] = *(const bf16x8*)(Bb + (size_t)nt * 16384 + kt + kk * 32);
    __syncthreads();
    #pragma unroll
    for (int kk = 0; kk < 2; kk++) {
      const int kc = kk * 4 + quad;
      bf16x8 af[4];
      #pragma unroll
      for (int mt = 0; mt < 4; mt++) {
        const int row = wrow + mt * 16 + lrow;
        af[mt] = *(const bf16x8*)&sA[row * 128 + ((kc ^ (row & 7)) << 4)];
      }
      #pragma unroll
      for (int mt = 0; mt < 4; mt++)
        #pragma unroll
        for (int nt = 0; nt < 4; nt++)
          acc[mt][nt] = __builtin_amdgcn_mfma_f32_16x16x32_bf16(af[mt], bfr[kk][nt], acc[mt][nt], 0, 0, 0);
    }
  }

  const int grow = m0 + wrow;
  #pragma unroll
  for (int mt = 0; mt < 4; mt++) {
    #pragma unroll
    for (int nt = 0; nt < 4; nt++) {
      const int c = n0 + wcol + nt * 16 + lrow;
      #pragma unroll
      for (int r = 0; r < 4; r++)
        C[(size_t)(grow + mt * 16 + quad * 4 + r) * 1024 + c] = acc[mt][nt][r];
    }
  }
}

extern "C" void kernel_launch(void* const* d_in, const int* in_sizes, int n_in,
                              void* d_out, int out_size, void* d_ws, size_t ws_size,
                              hipStream_t stream) {
  const float* x  = (const float*)d_in[0];
  const float* Wq = (const float*)d_in[1];
  const float* Wk = (const float*)d_in[2];
  const float* Wv = (const float*)d_in[3];
  const float* Wo = (const float*)d_in[4];
  float* out = (float*)d_out;

  char* ws = (char*)d_ws;
  size_t off = 0;
  auto alloc = [&](size_t bytes) -> char* {
    char* p = ws + off;
    off += (bytes + 255) & ~(size_t)255;
    return p;
  };

  unsigned short* xb    = (unsigned short*)alloc((size_t)16384 * 1024 * 2);
  unsigned short* WcatT = (unsigned short*)alloc((size_t)3072 * 1024 * 2);
  unsigned short* WoT   = (unsigned short*)alloc((size_t)1024 * 1024 * 2);
  float* cosT           = (float*)alloc((size_t)4096 * 32 * 4);
  float* sinT           = (float*)alloc((size_t)4096 * 32 * 4);
  unsigned short* Qd    = (unsigned short*)alloc((size_t)16384 * 1024 * 2);
  unsigned short* KTd   = (unsigned short*)alloc((size_t)64 * 64 * 4096 * 2);
  unsigned short* VTd   = (unsigned short*)alloc((size_t)64 * 64 * 4096 * 2);
  float* vkp            = (float*)alloc((size_t)512 * 5120 * 4);
  unsigned short* vkb   = (unsigned short*)alloc((size_t)64 * 5120 * 2);
  unsigned short* attn  = xb; // xb dead after gemm_qkv

  prep_kernel<<<16384 + 512 + 4096, 256, 0, stream>>>(x, Wq, Wk, Wv, Wo, xb, WcatT, WoT, cosT, sinT);
  gemm_qkv_kernel<<<dim3(128, 24), 256, 0, stream>>>(xb, WcatT, cosT, sinT, Qd, KTd, VTd);
  vk_partial_kernel<<<dim3(64, 8), 256, 0, stream>>>(KTd, VTd, vkp);
  vk_reduce_kernel<<<1280, 256, 0, stream>>>(vkp, vkb);
  attn_kernel<<<dim3(16, 64), 256, 0, stream>>>(Qd, vkb, attn);
  gemm_out_kernel<<<dim3(128, 8), 256, 0, stream>>>(attn, WoT, out);
}

// Round 4
// 329.939 us; speedup vs baseline: 1.4565x; 1.4565x over previous
//
#include <hip/hip_runtime.h>
#include <stdint.h>

#define GLOBAL_AS __attribute__((address_space(1)))
#define LDS_AS __attribute__((address_space(3)))

typedef float f32x4 __attribute__((ext_vector_type(4)));
typedef short bf16x8 __attribute__((ext_vector_type(8)));

static __device__ __forceinline__ unsigned short f2b(float f) {
  union { float f; unsigned u; } v; v.f = f;
  return (unsigned short)((v.u + 0x7FFFu + ((v.u >> 16) & 1u)) >> 16);
}

static __device__ __forceinline__ void async16(const void* g, void* l) {
  __builtin_amdgcn_global_load_lds((const GLOBAL_AS unsigned int*)g,
                                   (LDS_AS unsigned int*)l, 16, 0, 0);
}

// ---------------- fused prep: cast_x | rope table | 4x transpose-cast ----------------
__global__ void prep_kernel(const float* __restrict__ x,
                            const float* __restrict__ Wq, const float* __restrict__ Wk,
                            const float* __restrict__ Wv, const float* __restrict__ Wo,
                            unsigned short* __restrict__ xb,
                            unsigned short* __restrict__ WcatT, unsigned short* __restrict__ WoT,
                            float* __restrict__ cosT, float* __restrict__ sinT) {
  __shared__ float tile[32][33];
  const int bid = blockIdx.x;
  const int tid = threadIdx.x;
  if (bid < 16384) {
    const int i = bid * 256 + tid;
    float4 v = ((const float4*)x)[i];
    ushort4 o;
    o.x = f2b(v.x); o.y = f2b(v.y); o.z = f2b(v.z); o.w = f2b(v.w);
    ((ushort4*)xb)[i] = o;
  } else if (bid < 16384 + 512) {
    const int idx = (bid - 16384) * 256 + tid;
    const int s = idx >> 5, j = idx & 31;
    float freq = expf(-((float)(2 * j) * (1.0f / 64.0f)) * 9.210340371976184f);
    float ang = (float)s * freq;
    float sn, cs;
    sincosf(ang, &sn, &cs);
    cosT[idx] = cs;
    sinT[idx] = sn;
  } else {
    const int t = bid - 16896;
    const int mat = t >> 10;
    const int r = t & 1023;
    const int k0 = (r & 31) * 32, n0 = (r >> 5) * 32;
    const float* W = (mat == 0) ? Wq : (mat == 1) ? Wk : (mat == 2) ? Wv : Wo;
    unsigned short* WT = (mat < 3) ? (WcatT + (size_t)mat * 1024 * 1024) : WoT;
    const int tx = tid & 31, ty = tid >> 5;
    #pragma unroll
    for (int i = 0; i < 4; i++)
      tile[ty + i * 8][tx] = W[(size_t)(k0 + ty + i * 8) * 1024 + n0 + tx];
    __syncthreads();
    #pragma unroll
    for (int i = 0; i < 4; i++)
      WT[(size_t)(n0 + ty + i * 8) * 1024 + k0 + tx] = f2b(tile[tx][ty + i * 8]);
  }
}

// ---------------- fused QKV GEMM ----------------
// BK=64, XOR-swizzled LDS; launch_bounds(256,3) -> cap regs ~170 so 3 blocks/CU
// (acc[4][4] = 64 AGPRs counts against the unified file; at default we got 2 blocks/CU).
__global__ __launch_bounds__(256, 3)
void gemm_qkv_kernel(const unsigned short* __restrict__ xb,
                     const unsigned short* __restrict__ WT,
                     const float* __restrict__ cosT,
                     const float* __restrict__ sinT,
                     unsigned short* __restrict__ Qd,
                     unsigned short* __restrict__ KTd,
                     unsigned short* __restrict__ VTd) {
  __shared__ char sA[16384];
  __shared__ char sB[16384];
  const int tid = threadIdx.x;
  const int lane = tid & 63;
  const int wave = tid >> 6;
  const int lrow = lane & 15;
  const int quad = lane >> 4;
  const int m0 = blockIdx.x * 128;
  const int n0 = blockIdx.y * 128;
  const int wrow = (wave >> 1) * 64;
  const int wcol = (wave & 1) * 64;

  const f32x4 zf = {0.f, 0.f, 0.f, 0.f};
  f32x4 acc[4][4];
  #pragma unroll
  for (int i = 0; i < 4; i++)
    #pragma unroll
    for (int j = 0; j < 4; j++) acc[i][j] = zf;

  const int srow = tid >> 3;
  const int gcol = ((tid & 7) ^ (srow & 7)) * 8; // source-side swizzle chunk

  for (int kt = 0; kt < 1024; kt += 64) {
    __syncthreads();
    #pragma unroll
    for (int i = 0; i < 4; i++) {
      async16(xb + (size_t)(m0 + i * 32 + srow) * 1024 + kt + gcol, &sA[i * 4096 + tid * 16]);
      async16(WT + (size_t)(n0 + i * 32 + srow) * 1024 + kt + gcol, &sB[i * 4096 + tid * 16]);
    }
    __syncthreads();
    #pragma unroll
    for (int kk = 0; kk < 2; kk++) {
      const int kc = kk * 4 + quad;
      bf16x8 af[4], bfr[4];
      #pragma unroll
      for (int mt = 0; mt < 4; mt++) {
        const int row = wrow + mt * 16 + lrow;
        af[mt] = *(const bf16x8*)&sA[row * 128 + ((kc ^ (row & 7)) << 4)];
      }
      #pragma unroll
      for (int nt = 0; nt < 4; nt++) {
        const int row = wcol + nt * 16 + lrow;
        bfr[nt] = *(const bf16x8*)&sB[row * 128 + ((kc ^ (row & 7)) << 4)];
      }
      #pragma unroll
      for (int mt = 0; mt < 4; mt++)
        #pragma unroll
        for (int nt = 0; nt < 4; nt++)
          acc[mt][nt] = __builtin_amdgcn_mfma_f32_16x16x32_bf16(af[mt], bfr[nt], acc[mt][nt], 0, 0, 0);
    }
  }

  const int b = m0 >> 12;
  const int sec = n0 >> 10;         // 0=Q 1=K 2=V
  const int s0 = (m0 & 4095) + wrow;
  const int c0 = (n0 & 1023) + wcol;

  if (sec == 2) {
    #pragma unroll
    for (int mt = 0; mt < 4; mt++) {
      const int sB4 = s0 + mt * 16 + quad * 4;
      #pragma unroll
      for (int nt = 0; nt < 4; nt++) {
        const int c = c0 + nt * 16 + lrow;
        const int h = c >> 6, e = c & 63;
        ushort4 pk;
        pk.x = f2b(acc[mt][nt][0]); pk.y = f2b(acc[mt][nt][1]);
        pk.z = f2b(acc[mt][nt][2]); pk.w = f2b(acc[mt][nt][3]);
        *(ushort4*)&VTd[((size_t)(b * 16 + h) * 64 + e) * 4096 + sB4] = pk;
      }
    }
  } else {
    #pragma unroll
    for (int mt = 0; mt < 4; mt++) {
      const int sB4 = s0 + mt * 16 + quad * 4;
      #pragma unroll
      for (int nt = 0; nt < 4; nt++) {
        const int c = c0 + nt * 16 + lrow;
        const int j = (c & 63) >> 1;
        float ov[4];
        #pragma unroll
        for (int r = 0; r < 4; r++) {
          const float v = acc[mt][nt][r];
          const float p = __shfl_xor(v, 1, 64);
          const int s = sB4 + r;
          const float cs = cosT[s * 32 + j];
          const float sn = sinT[s * 32 + j];
          const float t = (lane & 1) ? p * sn : -p * sn;
          ov[r] = fmaxf(fmaf(v, cs, t), 0.0f);
        }
        if (sec == 0) {
          const int grow = m0 + wrow + mt * 16 + quad * 4;
          #pragma unroll
          for (int r = 0; r < 4; r++)
            Qd[(size_t)(grow + r) * 1024 + c] = f2b(ov[r]);
        } else {
          const int h = c >> 6, d = c & 63;
          ushort4 pk;
          pk.x = f2b(ov[0]); pk.y = f2b(ov[1]); pk.z = f2b(ov[2]); pk.w = f2b(ov[3]);
          *(ushort4*)&KTd[((size_t)(b * 16 + h) * 64 + d) * 4096 + sB4] = pk;
        }
      }
    }
  }
}

// ---------------- vk = V_pad^T @ K  (per b,h; K-split partials) ----------------
__global__ __launch_bounds__(256)
void vk_partial_kernel(const unsigned short* __restrict__ KTd,
                       const unsigned short* __restrict__ VTd,
                       float* __restrict__ vkp) {
  __shared__ char sV[4096];
  __shared__ char sK[4096];
  const int tid = threadIdx.x;
  const int lane = tid & 63;
  const int wave = tid >> 6;
  const int lrow = lane & 15;
  const int quad = lane >> 4;
  const int bh = blockIdx.x;
  const int kb = blockIdx.y;
  const int s00 = kb * 512;

  const f32x4 zf = {0.f, 0.f, 0.f, 0.f};
  f32x4 acc[5];
  #pragma unroll
  for (int i = 0; i < 5; i++) acc[i] = zf;

  bf16x8 af4;
  const short oneb = (short)0x3F80;
  #pragma unroll
  for (int j = 0; j < 8; j++) af4[j] = (lrow == 0) ? oneb : (short)0;

  const int srow = tid >> 2;
  const int gcol = ((tid & 3) ^ (srow & 3)) * 8;

  for (int kt = 0; kt < 512; kt += 32) {
    __syncthreads();
    async16(VTd + ((size_t)bh * 64 + srow) * 4096 + s00 + kt + gcol, &sV[tid * 16]);
    async16(KTd + ((size_t)bh * 64 + srow) * 4096 + s00 + kt + gcol, &sK[tid * 16]);
    __syncthreads();
    const int rowK = wave * 16 + lrow;
    bf16x8 bfrag = *(const bf16x8*)&sK[rowK * 64 + ((quad ^ (rowK & 3)) << 4)];
    #pragma unroll
    for (int mt = 0; mt < 4; mt++) {
      const int rowV = mt * 16 + lrow;
      bf16x8 af = *(const bf16x8*)&sV[rowV * 64 + ((quad ^ (rowV & 3)) << 4)];
      acc[mt] = __builtin_amdgcn_mfma_f32_16x16x32_bf16(af, bfrag, acc[mt], 0, 0, 0);
    }
    acc[4] = __builtin_amdgcn_mfma_f32_16x16x32_bf16(af4, bfrag, acc[4], 0, 0, 0);
  }

  #pragma unroll
  for (int mt = 0; mt < 5; mt++) {
    #pragma unroll
    for (int r = 0; r < 4; r++) {
      const int e = mt * 16 + quad * 4 + r;
      const int d = wave * 16 + lrow;
      vkp[((size_t)(bh * 8 + kb) * 80 + e) * 64 + d] = acc[mt][r];
    }
  }
}

__global__ void vk_reduce_kernel(const float* __restrict__ vkp, unsigned short* __restrict__ vkb) {
  int idx = blockIdx.x * 256 + threadIdx.x;
  if (idx >= 64 * 80 * 64) return;
  int bh = idx / 5120, r = idx % 5120;
  float s = 0.f;
  #pragma unroll
  for (int kb = 0; kb < 8; kb++) s += vkp[(size_t)(bh * 8 + kb) * 5120 + r];
  vkb[idx] = f2b(s);
}

// ---------------- num + divide -> attn ----------------
__global__ __launch_bounds__(256)
void attn_kernel(const unsigned short* __restrict__ Qd,
                 const unsigned short* __restrict__ vkb,
                 unsigned short* __restrict__ attn) {
  __shared__ char sQ[32768];
  __shared__ char sVK[10240];
  const int tid = threadIdx.x;
  const int lane = tid & 63;
  const int wave = tid >> 6;
  const int lrow = lane & 15;
  const int quad = lane >> 4;
  const int bh = blockIdx.y, b = bh >> 4, h = bh & 15;
  const int l0 = b * 4096 + blockIdx.x * 256;

  const int c4 = tid & 7;
  #pragma unroll
  for (int r = 0; r < 8; r++) {
    const int o = r * 4096 + tid * 16;
    const int row = o >> 7;
    const int g4 = c4 ^ (row & 7);
    async16(Qd + (size_t)(l0 + row) * 1024 + h * 64 + g4 * 8, &sQ[o]);
  }
  {
    int row = tid >> 3;
    int g4 = c4 ^ (row & 7);
    async16(vkb + (size_t)bh * 5120 + row * 64 + g4 * 8, &sVK[tid * 16]);
    row += 32; g4 = c4 ^ (row & 7);
    async16(vkb + (size_t)bh * 5120 + row * 64 + g4 * 8, &sVK[4096 + tid * 16]);
    if (tid < 128) {
      row = 64 + (tid >> 3); g4 = c4 ^ (row & 7);
      async16(vkb + (size_t)bh * 5120 + row * 64 + g4 * 8, &sVK[8192 + tid * 16]);
    }
  }
  __syncthreads();

  const f32x4 zf = {0.f, 0.f, 0.f, 0.f};
  f32x4 acc[4][5];
  #pragma unroll
  for (int i = 0; i < 4; i++)
    #pragma unroll
    for (int j = 0; j < 5; j++) acc[i][j] = zf;

  #pragma unroll
  for (int kk = 0; kk < 2; kk++) {
    const int kc = kk * 4 + quad;
    bf16x8 af[4], bfr[5];
    #pragma unroll
    for (int mt = 0; mt < 4; mt++) {
      const int row = wave * 64 + mt * 16 + lrow;
      af[mt] = *(const bf16x8*)&sQ[row * 128 + ((kc ^ (row & 7)) << 4)];
    }
    #pragma unroll
    for (int nt = 0; nt < 5; nt++) {
      const int row = nt * 16 + lrow;
      bfr[nt] = *(const bf16x8*)&sVK[row * 128 + ((kc ^ (row & 7)) << 4)];
    }
    #pragma unroll
    for (int mt = 0; mt < 4; mt++)
      #pragma unroll
      for (int nt = 0; nt < 5; nt++)
        acc[mt][nt] = __builtin_amdgcn_mfma_f32_16x16x32_bf16(af[mt], bfr[nt], acc[mt][nt], 0, 0, 0);
  }

  #pragma unroll
  for (int mt = 0; mt < 4; mt++) {
    #pragma unroll
    for (int r = 0; r < 4; r++) {
      const float den = __shfl(acc[mt][4][r], lane & 48, 64);
      const float inv = 1.0f / (den + 1e-6f);
      const int l = l0 + wave * 64 + mt * 16 + quad * 4 + r;
      #pragma unroll
      for (int nt = 0; nt < 4; nt++)
        attn[(size_t)l * 1024 + h * 64 + nt * 16 + lrow] = f2b(acc[mt][nt][r] * inv);
    }
  }
}

// ---------------- out = attn @ Wo ----------------
__global__ __launch_bounds__(256, 3)
void gemm_out_kernel(const unsigned short* __restrict__ A,
                     const unsigned short* __restrict__ BT,
                     float* __restrict__ C) {
  __shared__ char sA[16384];
  __shared__ char sB[16384];
  const int tid = threadIdx.x;
  const int lane = tid & 63;
  const int wave = tid >> 6;
  const int lrow = lane & 15;
  const int quad = lane >> 4;
  const int m0 = blockIdx.x * 128;
  const int n0 = blockIdx.y * 128;
  const int wrow = (wave >> 1) * 64;
  const int wcol = (wave & 1) * 64;

  const f32x4 zf = {0.f, 0.f, 0.f, 0.f};
  f32x4 acc[4][4];
  #pragma unroll
  for (int i = 0; i < 4; i++)
    #pragma unroll
    for (int j = 0; j < 4; j++) acc[i][j] = zf;

  const int srow = tid >> 3;
  const int gcol = ((tid & 7) ^ (srow & 7)) * 8;

  for (int kt = 0; kt < 1024; kt += 64) {
    __syncthreads();
    #pragma unroll
    for (int i = 0; i < 4; i++) {
      async16(A + (size_t)(m0 + i * 32 + srow) * 1024 + kt + gcol, &sA[i * 4096 + tid * 16]);
      async16(BT + (size_t)(n0 + i * 32 + srow) * 1024 + kt + gcol, &sB[i * 4096 + tid * 16]);
    }
    __syncthreads();
    #pragma unroll
    for (int kk = 0; kk < 2; kk++) {
      const int kc = kk * 4 + quad;
      bf16x8 af[4], bfr[4];
      #pragma unroll
      for (int mt = 0; mt < 4; mt++) {
        const int row = wrow + mt * 16 + lrow;
        af[mt] = *(const bf16x8*)&sA[row * 128 + ((kc ^ (row & 7)) << 4)];
      }
      #pragma unroll
      for (int nt = 0; nt < 4; nt++) {
        const int row = wcol + nt * 16 + lrow;
        bfr[nt] = *(const bf16x8*)&sB[row * 128 + ((kc ^ (row & 7)) << 4)];
      }
      #pragma unroll
      for (int mt = 0; mt < 4; mt++)
        #pragma unroll
        for (int nt = 0; nt < 4; nt++)
          acc[mt][nt] = __builtin_amdgcn_mfma_f32_16x16x32_bf16(af[mt], bfr[kk * 0 + nt], acc[mt][nt], 0, 0, 0);
    }
  }

  const int grow = m0 + wrow;
  #pragma unroll
  for (int mt = 0; mt < 4; mt++) {
    #pragma unroll
    for (int nt = 0; nt < 4; nt++) {
      const int c = n0 + wcol + nt * 16 + lrow;
      #pragma unroll
      for (int r = 0; r < 4; r++)
        C[(size_t)(grow + mt * 16 + quad * 4 + r) * 1024 + c] = acc[mt][nt][r];
    }
  }
}

extern "C" void kernel_launch(void* const* d_in, const int* in_sizes, int n_in,
                              void* d_out, int out_size, void* d_ws, size_t ws_size,
                              hipStream_t stream) {
  const float* x  = (const float*)d_in[0];
  const float* Wq = (const float*)d_in[1];
  const float* Wk = (const float*)d_in[2];
  const float* Wv = (const float*)d_in[3];
  const float* Wo = (const float*)d_in[4];
  float* out = (float*)d_out;

  char* ws = (char*)d_ws;
  size_t off = 0;
  auto alloc = [&](size_t bytes) -> char* {
    char* p = ws + off;
    off += (bytes + 255) & ~(size_t)255;
    return p;
  };

  unsigned short* xb    = (unsigned short*)alloc((size_t)16384 * 1024 * 2);
  unsigned short* WcatT = (unsigned short*)alloc((size_t)3072 * 1024 * 2);
  unsigned short* WoT   = (unsigned short*)alloc((size_t)1024 * 1024 * 2);
  float* cosT           = (float*)alloc((size_t)4096 * 32 * 4);
  float* sinT           = (float*)alloc((size_t)4096 * 32 * 4);
  unsigned short* Qd    = (unsigned short*)alloc((size_t)16384 * 1024 * 2);
  unsigned short* KTd   = (unsigned short*)alloc((size_t)64 * 64 * 4096 * 2);
  unsigned short* VTd   = (unsigned short*)alloc((size_t)64 * 64 * 4096 * 2);
  float* vkp            = (float*)alloc((size_t)512 * 5120 * 4);
  unsigned short* vkb   = (unsigned short*)alloc((size_t)64 * 5120 * 2);
  unsigned short* attn  = xb; // xb dead after gemm_qkv

  prep_kernel<<<16384 + 512 + 4096, 256, 0, stream>>>(x, Wq, Wk, Wv, Wo, xb, WcatT, WoT, cosT, sinT);
  gemm_qkv_kernel<<<dim3(128, 24), 256, 0, stream>>>(xb, WcatT, cosT, sinT, Qd, KTd, VTd);
  vk_partial_kernel<<<dim3(64, 8), 256, 0, stream>>>(KTd, VTd, vkp);
  vk_reduce_kernel<<<1280, 256, 0, stream>>>(vkp, vkb);
  attn_kernel<<<dim3(16, 64), 256, 0, stream>>>(Qd, vkb, attn);
  gemm_out_kernel<<<dim3(128, 8), 256, 0, stream>>>(attn, WoT, out);
}